// Round 1
// baseline (146.300 us; speedup 1.0000x reference)
//
#include <hip/hip_runtime.h>
#include <hip/hip_bf16.h>
#include <stdint.h>

// BCM_Linear: out[t, r*64+i] = sum_{q,j} x[t, q*64+j] * w[r, q, (i-j)%64]
// == GEMM out = x @ W^T,  W[o,k] = w[o>>6, k>>6, (o-k)&63]  (1024x1024)
// M=32768, N=1024, K=1024, fp32 in/out, bf16 MFMA compute (threshold 1.5e-1).

#define NTOK 32768
#define NCH  1024

typedef short bf16x8 __attribute__((ext_vector_type(8)));   // 8 bf16 in 4 VGPRs
typedef float f32x4  __attribute__((ext_vector_type(4)));
typedef unsigned short u16x8 __attribute__((ext_vector_type(8)));

static __device__ __forceinline__ unsigned short f2bf(float f) {
    // round-to-nearest-even fp32 -> bf16
    unsigned int u = __float_as_uint(f);
    u += 0x7FFFu + ((u >> 16) & 1u);
    return (unsigned short)(u >> 16);
}

// ---------------- kernel 1: x fp32 -> bf16 ----------------
__global__ void cvt_x_kernel(const float* __restrict__ x, u16x8* __restrict__ xb, int n8) {
    int stride = gridDim.x * blockDim.x;
    for (int i = blockIdx.x * blockDim.x + threadIdx.x; i < n8; i += stride) {
        float4 a = ((const float4*)x)[2 * i];
        float4 b = ((const float4*)x)[2 * i + 1];
        u16x8 v;
        v[0] = f2bf(a.x); v[1] = f2bf(a.y); v[2] = f2bf(a.z); v[3] = f2bf(a.w);
        v[4] = f2bf(b.x); v[5] = f2bf(b.y); v[6] = f2bf(b.z); v[7] = f2bf(b.w);
        xb[i] = v;
    }
}

// ---------------- kernel 2: expand circulant w -> dense bf16 W (N x K) ----------------
__global__ void build_w_kernel(const float* __restrict__ w, unsigned short* __restrict__ Wb) {
    int idx = blockIdx.x * blockDim.x + threadIdx.x;   // 0 .. 1024*1024-1
    int o = idx >> 10;         // out channel (row of W)
    int k = idx & 1023;        // in channel  (col of W)
    int r = o >> 6, q = k >> 6;
    int d = (o - k) & 63;      // == ((o&63)-(k&63)) mod 64
    Wb[idx] = f2bf(w[(r * 16 + q) * 64 + d]);
}

// ---------------- kernel 3: bf16 GEMM, C = A * B^T ----------------
// A: M x K bf16 row-major (x), B: N x K bf16 row-major (W), C: M x N fp32.
// m97 structure: 128x128 tile, BK=32, 4 waves (2x2, 64x64 each),
// global_load_lds width=16 staging, linear LDS, mfma_f32_16x16x32_bf16.

#define GLOAD16(gp, lp)                                                            \
    __builtin_amdgcn_global_load_lds(                                              \
        (const __attribute__((address_space(1))) unsigned int*)(gp),               \
        (__attribute__((address_space(3))) unsigned int*)(lp), 16, 0, 0)

__global__ void __launch_bounds__(256) gemm_kernel(const unsigned short* __restrict__ A,
                                                   const unsigned short* __restrict__ B,
                                                   float* __restrict__ C) {
    constexpr int K = NCH, N = NCH;
    constexpr int BK = 32;
    __shared__ unsigned short As[128 * BK];   // 8 KB, linear [row][k]
    __shared__ unsigned short Bs[128 * BK];   // 8 KB

    // XCD-chunked swizzle: 2048 blocks, 8 XCDs, 256 contiguous work-items per XCD
    int bid  = blockIdx.x;
    int cpx  = gridDim.x >> 3;
    int wid  = (bid & 7) * cpx + (bid >> 3);
    int tile_n = wid & 7;        // N/128 = 8  (fast dim -> blocks sharing A-tile stay on one XCD)
    int tile_m = wid >> 3;
    int m0 = tile_m * 128, n0 = tile_n * 128;

    int tid  = threadIdx.x;
    int lane = tid & 63;
    int wv   = tid >> 6;               // 0..3
    int wr   = wv >> 1, wc = wv & 1;   // 2x2 waves, 64x64 output each

    f32x4 acc[4][4];
#pragma unroll
    for (int m = 0; m < 4; ++m)
#pragma unroll
        for (int n = 0; n < 4; ++n) acc[m][n] = (f32x4)0.f;

    const unsigned short* Abase = A + (size_t)m0 * K;
    const unsigned short* Bbase = B + (size_t)n0 * K;

    // staging: each pass covers 128x32 bf16 = 8192 B in 2 half-tile passes of 256 lanes x 16 B
    int srow = tid >> 2;             // 0..63   (row within half-tile)
    int scol = (tid & 3) << 3;       // 0,8,16,24  (k offset, 8 bf16 = 16 B)

    // LDS fragment read offsets (bytes); row stride = BK*2 = 64 B
    int kq    = lane >> 4;                       // k-quarter 0..3
    int a_off = (wr * 64 + (lane & 15)) * 64 + kq * 16;
    int b_off = (wc * 64 + (lane & 15)) * 64 + kq * 16;

    for (int kt = 0; kt < K; kt += BK) {
        __syncthreads();
        {
            const unsigned short* ga = Abase + (size_t)srow * K + kt + scol;
            const unsigned short* gb = Bbase + (size_t)srow * K + kt + scol;
            GLOAD16(ga,          (char*)As + (wv << 10));           // rows 0..63
            GLOAD16(ga + 64 * K, (char*)As + 4096 + (wv << 10));    // rows 64..127
            GLOAD16(gb,          (char*)Bs + (wv << 10));
            GLOAD16(gb + 64 * K, (char*)Bs + 4096 + (wv << 10));
        }
        __syncthreads();

        bf16x8 af[4], bfr[4];
#pragma unroll
        for (int m = 0; m < 4; ++m)
            af[m] = *(const bf16x8*)((const char*)As + a_off + m * 16 * 64);
#pragma unroll
        for (int n = 0; n < 4; ++n)
            bfr[n] = *(const bf16x8*)((const char*)Bs + b_off + n * 16 * 64);

#pragma unroll
        for (int m = 0; m < 4; ++m)
#pragma unroll
            for (int n = 0; n < 4; ++n)
                acc[m][n] = __builtin_amdgcn_mfma_f32_16x16x32_bf16(af[m], bfr[n], acc[m][n], 0, 0, 0);
    }

    // epilogue: C/D layout col = lane&15, row = (lane>>4)*4 + j   [m89/m91-verified]
    float* Cb = C + (size_t)(m0 + wr * 64) * N + n0 + wc * 64;
    int cc = lane & 15;
#pragma unroll
    for (int m = 0; m < 4; ++m) {
        int r0 = m * 16 + (lane >> 4) * 4;
#pragma unroll
        for (int j = 0; j < 4; ++j) {
            float* rowp = Cb + (size_t)(r0 + j) * N;
#pragma unroll
            for (int n = 0; n < 4; ++n)
                rowp[n * 16 + cc] = acc[m][n][j];
        }
    }
}

// ---------------- fallback (ws too small): naive fp32, correct but slow ----------------
__global__ void naive_kernel(const float* __restrict__ x, const float* __restrict__ w,
                             float* __restrict__ out) {
    int t = blockIdx.x;
    int o = blockIdx.y * 256 + threadIdx.x;
    const float* xr = x + (size_t)t * NCH;
    int r = o >> 6, oi = o & 63;
    float s = 0.f;
    for (int q = 0; q < 16; ++q) {
        const float* wq = w + (r * 16 + q) * 64;
        const float* xq = xr + q * 64;
#pragma unroll 8
        for (int j = 0; j < 64; ++j) s += xq[j] * wq[(oi - j) & 63];
    }
    out[(size_t)t * NCH + o] = s;
}

extern "C" void kernel_launch(void* const* d_in, const int* in_sizes, int n_in,
                              void* d_out, int out_size, void* d_ws, size_t ws_size,
                              hipStream_t stream) {
    const float* x = (const float*)d_in[0];
    const float* w = (const float*)d_in[1];
    float* out = (float*)d_out;

    const size_t needX = (size_t)NTOK * NCH * sizeof(unsigned short);  // 64 MB
    const size_t needW = (size_t)NCH * NCH * sizeof(unsigned short);   //  2 MB

    if (ws_size >= needX + needW) {
        unsigned short* xb = (unsigned short*)d_ws;
        unsigned short* Wb = (unsigned short*)((char*)d_ws + needX);
        hipLaunchKernelGGL(cvt_x_kernel, dim3(2048), dim3(256), 0, stream,
                           x, (u16x8*)xb, NTOK * NCH / 8);
        hipLaunchKernelGGL(build_w_kernel, dim3(4096), dim3(256), 0, stream, w, Wb);
        hipLaunchKernelGGL(gemm_kernel, dim3(2048), dim3(256), 0, stream, xb, Wb, out);
    } else {
        hipLaunchKernelGGL(naive_kernel, dim3(NTOK, 4), dim3(256), 0, stream, x, w, out);
    }
}

// Round 2
// 114.127 us; speedup vs baseline: 1.2819x; 1.2819x over previous
//
#include <hip/hip_runtime.h>
#include <stdint.h>

// BCM_Linear: out = x @ W^T, W[o,k] = w[o>>6, k>>6, (o-k)&63]  (1024x1024)
// M=32768, N=1024, K=1024. bf16 MFMA compute, fp32 out.
// 256x256 8-phase template (T1 XCD-swizzle + T2 LDS st-swizzle via pre-swizzled
// global arrays + T3/T4 counted-vmcnt phase pipeline + T5 setprio).

#define NTOK 32768
#define NCH  1024
#define BK   64
#define NKT  (NCH / BK)   // 16

typedef short bf16x8 __attribute__((ext_vector_type(8)));
typedef float f32x4  __attribute__((ext_vector_type(4)));
typedef unsigned short u16x8 __attribute__((ext_vector_type(8)));

static __device__ __forceinline__ unsigned short f2bf(float f) {
    unsigned int u = __float_as_uint(f);
    u += 0x7FFFu + ((u >> 16) & 1u);
    return (unsigned short)(u >> 16);
}

#define GLOAD16(gp, lp)                                                          \
    __builtin_amdgcn_global_load_lds(                                            \
        (const __attribute__((address_space(1))) unsigned int*)(gp),             \
        (__attribute__((address_space(3))) unsigned int*)(lp), 16, 0, 0)

// ---------------- kernel 1: x fp32 -> bf16, pre-swizzled ----------------
// xb[row][c] = bf16(x[row][c ^ ((row&7)<<4 bytes)]) within each 128B K-chunk:
// 16B-block j goes to block (j&~7) | ((j&7)^(row&7)).
__global__ void cvt_x_kernel(const float* __restrict__ x, unsigned short* __restrict__ xb) {
    int i = blockIdx.x * blockDim.x + threadIdx.x;   // 0 .. NTOK*128-1
    int row = i >> 7;
    int j   = i & 127;
    const float4* src = (const float4*)(x + (((size_t)row) << 10) + (j << 3));
    float4 a = src[0], b = src[1];
    u16x8 v;
    v[0]=f2bf(a.x); v[1]=f2bf(a.y); v[2]=f2bf(a.z); v[3]=f2bf(a.w);
    v[4]=f2bf(b.x); v[5]=f2bf(b.y); v[6]=f2bf(b.z); v[7]=f2bf(b.w);
    int js = (j & ~7) | ((j & 7) ^ (row & 7));
    *(u16x8*)(xb + (((size_t)row) << 10) + (js << 3)) = v;
}

// ---------------- kernel 2: circulant w -> dense bf16 W (N x K), pre-swizzled ----------------
__global__ void build_w_kernel(const float* __restrict__ w, unsigned short* __restrict__ Wb) {
    int i = blockIdx.x * blockDim.x + threadIdx.x;   // 0 .. 1024*128-1
    int o = i >> 7;
    int j = i & 127;
    int r = o >> 6;
    int q = j >> 3;                 // (j*8)>>6
    const float* wrow = w + ((r * 16 + q) << 6);
    int k0 = j << 3;
    u16x8 v;
#pragma unroll
    for (int e = 0; e < 8; ++e) v[e] = f2bf(wrow[(o - (k0 + e)) & 63]);
    int js = (j & ~7) | ((j & 7) ^ (o & 7));
    *(u16x8*)(Wb + (((size_t)o) << 10) + (js << 3)) = v;
}

// ---------------- kernel 3: 256x256 8-phase GEMM ----------------
#define PHASE_BAR() __builtin_amdgcn_s_barrier()
#define LGKM0() asm volatile("s_waitcnt lgkmcnt(0)" ::: "memory")
#define VMCNT(n) asm volatile("s_waitcnt vmcnt(" #n ")" ::: "memory")
#define SETPRIO(n) __builtin_amdgcn_s_setprio(n)
#define MFMA4(d, av, bv) d = __builtin_amdgcn_mfma_f32_16x16x32_bf16(av, bv, d, 0, 0, 0)

// stage one half-tile (128 rows x 64 cols bf16 = 16 KB): 2 gload16/thread.
// src: per-thread base = mat + (base_row + tid>>3)*2048 + (tid&7)*16 (pre-swizzled array)
// lds: wave-uniform base; HW adds lane*16.
#define STAGE_HALF(src, ldsbuf, t, h) do {                                       \
    const char* _s = (src) + (((size_t)(h)) << 18) + (((size_t)(t)) << 7);       \
    char* _d = (ldsbuf) + ((h) << 14) + (wv << 10);                              \
    GLOAD16(_s, _d);                                                             \
    GLOAD16(_s + ((size_t)64 << 11), _d + 8192);                                 \
} while (0)

#define NOSTG ((void)0)

// One K-tile = 4 phases. Reads: P1 A(m0-3)+B(n0-1)=12, P2 B(n2-3)=4, P3 A(m4-7)=8, P4 none.
// MFMA quadrants: q1=m03xn01, q2=m03xn23, q3=m47xn01, q4=m47xn23 (16 each, K=64).
// Stage hooks S1..S4 issue one half-tile each; W4 = vmcnt before P4 barrier.
#define KTILE(Abuf, Bbuf, S1, S2, S3, S4, W4)                                    \
  do {                                                                           \
    bf16x8 afr[4][2], bfr[4][2];                                                 \
    _Pragma("unroll") for (int m = 0; m < 4; ++m)                                \
      _Pragma("unroll") for (int ks = 0; ks < 2; ++ks)                           \
        afr[m][ks] = *(const bf16x8*)((Abuf) + a_off[ks] + m * 2048);            \
    _Pragma("unroll") for (int n = 0; n < 2; ++n)                                \
      _Pragma("unroll") for (int ks = 0; ks < 2; ++ks)                           \
        bfr[n][ks] = *(const bf16x8*)((Bbuf) + b_off[ks] + n * 2048);            \
    S1;                                                                          \
    PHASE_BAR(); LGKM0();                                                        \
    SETPRIO(1);                                                                  \
    _Pragma("unroll") for (int m = 0; m < 4; ++m)                                \
      _Pragma("unroll") for (int n = 0; n < 2; ++n) {                            \
        MFMA4(acc[m][n], afr[m][0], bfr[n][0]);                                  \
        MFMA4(acc[m][n], afr[m][1], bfr[n][1]);                                  \
      }                                                                          \
    SETPRIO(0); PHASE_BAR();                                                     \
    /* P2 */                                                                     \
    _Pragma("unroll") for (int n = 2; n < 4; ++n)                                \
      _Pragma("unroll") for (int ks = 0; ks < 2; ++ks)                           \
        bfr[n][ks] = *(const bf16x8*)((Bbuf) + b_off[ks] + n * 2048);            \
    S2;                                                                          \
    PHASE_BAR(); LGKM0();                                                        \
    SETPRIO(1);                                                                  \
    _Pragma("unroll") for (int m = 0; m < 4; ++m)                                \
      _Pragma("unroll") for (int n = 2; n < 4; ++n) {                            \
        MFMA4(acc[m][n], afr[m][0], bfr[n][0]);                                  \
        MFMA4(acc[m][n], afr[m][1], bfr[n][1]);                                  \
      }                                                                          \
    SETPRIO(0); PHASE_BAR();                                                     \
    /* P3 */                                                                     \
    _Pragma("unroll") for (int m = 0; m < 4; ++m)                                \
      _Pragma("unroll") for (int ks = 0; ks < 2; ++ks)                           \
        afr[m][ks] = *(const bf16x8*)((Abuf) + a_off[ks] + (m + 4) * 2048);      \
    S3;                                                                          \
    PHASE_BAR(); LGKM0();                                                        \
    SETPRIO(1);                                                                  \
    _Pragma("unroll") for (int m = 0; m < 4; ++m)                                \
      _Pragma("unroll") for (int n = 0; n < 2; ++n) {                            \
        MFMA4(acc[m + 4][n], afr[m][0], bfr[n][0]);                              \
        MFMA4(acc[m + 4][n], afr[m][1], bfr[n][1]);                              \
      }                                                                          \
    SETPRIO(0); PHASE_BAR();                                                     \
    /* P4 */                                                                     \
    S4; W4;                                                                      \
    PHASE_BAR();                                                                 \
    SETPRIO(1);                                                                  \
    _Pragma("unroll") for (int m = 0; m < 4; ++m)                                \
      _Pragma("unroll") for (int n = 2; n < 4; ++n) {                            \
        MFMA4(acc[m + 4][n], afr[m][0], bfr[n][0]);                              \
        MFMA4(acc[m + 4][n], afr[m][1], bfr[n][1]);                              \
      }                                                                          \
    SETPRIO(0); PHASE_BAR();                                                     \
  } while (0)

__global__ void __launch_bounds__(512, 1) gemm8_kernel(const unsigned short* __restrict__ A,
                                                       const unsigned short* __restrict__ B,
                                                       float* __restrict__ C) {
    __shared__ __align__(16) char lds[131072];
    char* As0 = lds;                // A buf0: 256 rows x 128 B
    char* As1 = lds + 32768;
    char* Bs0 = lds + 65536;
    char* Bs1 = lds + 98304;

    int tid  = threadIdx.x;
    int lane = tid & 63;
    int wv   = tid >> 6;       // 0..7
    int wr   = wv >> 2;        // 0..1  (M-warps)
    int wc   = wv & 3;         // 0..3  (N-warps)

    // T1: XCD-chunked swizzle (512 blocks, 512%8==0 -> bijective)
    int cpx = gridDim.x >> 3;
    int wid = ((int)blockIdx.x & 7) * cpx + ((int)blockIdx.x >> 3);
    int tn = wid & 3, tm = wid >> 2;   // n fast: same-XCD neighbors share A panel
    int m0 = tm * 256, n0 = tn * 256;

    // staging source bases (arrays are pre-swizzled -> linear gather)
    const char* srcA = (const char*)A + (((size_t)(m0 + (tid >> 3))) << 11) + ((tid & 7) << 4);
    const char* srcB = (const char*)B + (((size_t)(n0 + (tid >> 3))) << 11) + ((tid & 7) << 4);

    // T2: swizzled ds_read offsets. row stride 128 B; inrow = (ks*64 + kq*16) ^ ((row&7)<<4)
    int xr   = (lane & 7) << 4;
    int kq16 = (lane >> 4) << 4;
    int a_off[2], b_off[2];
    {
        int arow = ((wr << 7) + (lane & 15)) << 7;
        int brow = ((wc << 6) + (lane & 15)) << 7;
        a_off[0] = arow + ((kq16 + 0)  ^ xr);
        a_off[1] = arow + ((kq16 + 64) ^ xr);
        b_off[0] = brow + ((kq16 + 0)  ^ xr);
        b_off[1] = brow + ((kq16 + 64) ^ xr);
    }

    f32x4 acc[8][4] = {};

    // prologue: t0 full + t1.B; leave t1.B (4 loads) outstanding
    STAGE_HALF(srcA, As0, 0, 0); STAGE_HALF(srcA, As0, 0, 1);
    STAGE_HALF(srcB, Bs0, 0, 0); STAGE_HALF(srcB, Bs0, 0, 1);
    STAGE_HALF(srcB, Bs1, 1, 0); STAGE_HALF(srcB, Bs1, 1, 1);
    VMCNT(4); PHASE_BAR();

    // main: pairs (t, t+1), t = 0..12. Stage slots (write-after-read safe):
    //  t.P1/P2 -> (t+1).A into other buf; t.P3/P4 -> (t+2).B into current buf
    for (int t = 0; t < NKT - 2; t += 2) {
        KTILE(As0, Bs0,
              STAGE_HALF(srcA, As1, t + 1, 0),
              STAGE_HALF(srcA, As1, t + 1, 1),
              STAGE_HALF(srcB, Bs0, t + 2, 0),
              STAGE_HALF(srcB, Bs0, t + 2, 1),
              VMCNT(4));
        KTILE(As1, Bs1,
              STAGE_HALF(srcA, As0, t + 2, 0),
              STAGE_HALF(srcA, As0, t + 2, 1),
              STAGE_HALF(srcB, Bs1, t + 3, 0),
              STAGE_HALF(srcB, Bs1, t + 3, 1),
              VMCNT(4));
    }
    // peeled final pair (14, 15): no B prefetch, drain for t15.A
    KTILE(As0, Bs0,
          STAGE_HALF(srcA, As1, NKT - 1, 0),
          STAGE_HALF(srcA, As1, NKT - 1, 1),
          NOSTG, NOSTG, VMCNT(0));
    KTILE(As1, Bs1, NOSTG, NOSTG, NOSTG, NOSTG, NOSTG);

    // epilogue: C/D layout col = lane&15, row = (lane>>4)*4 + j
    float* Cp = C + ((size_t)(m0 + wr * 128)) * NCH + n0 + wc * 64;
    int cc = lane & 15;
    int rr = (lane >> 4) << 2;
#pragma unroll
    for (int m = 0; m < 8; ++m)
#pragma unroll
        for (int j = 0; j < 4; ++j) {
            float* rowp = Cp + ((size_t)(m * 16 + rr + j)) * NCH;
#pragma unroll
            for (int n = 0; n < 4; ++n)
                rowp[n * 16 + cc] = acc[m][n][j];
        }
}

// ---------------- fallback (ws too small): naive fp32 ----------------
__global__ void naive_kernel(const float* __restrict__ x, const float* __restrict__ w,
                             float* __restrict__ out) {
    int t = blockIdx.x;
    int o = blockIdx.y * 256 + threadIdx.x;
    const float* xr = x + (size_t)t * NCH;
    int r = o >> 6, oi = o & 63;
    float s = 0.f;
    for (int q = 0; q < 16; ++q) {
        const float* wq = w + (r * 16 + q) * 64;
        const float* xq = xr + q * 64;
#pragma unroll 8
        for (int j = 0; j < 64; ++j) s += xq[j] * wq[(oi - j) & 63];
    }
    out[(size_t)t * NCH + o] = s;
}

extern "C" void kernel_launch(void* const* d_in, const int* in_sizes, int n_in,
                              void* d_out, int out_size, void* d_ws, size_t ws_size,
                              hipStream_t stream) {
    const float* x = (const float*)d_in[0];
    const float* w = (const float*)d_in[1];
    float* out = (float*)d_out;

    const size_t needX = (size_t)NTOK * NCH * sizeof(unsigned short);  // 64 MB
    const size_t needW = (size_t)NCH * NCH * sizeof(unsigned short);   //  2 MB

    if (ws_size >= needX + needW) {
        unsigned short* xb = (unsigned short*)d_ws;
        unsigned short* Wb = (unsigned short*)((char*)d_ws + needX);
        hipLaunchKernelGGL(cvt_x_kernel, dim3(NTOK * 128 / 256), dim3(256), 0, stream, x, xb);
        hipLaunchKernelGGL(build_w_kernel, dim3(NCH * 128 / 256), dim3(256), 0, stream, w, Wb);
        hipLaunchKernelGGL(gemm8_kernel, dim3(512), dim3(512), 0, stream, xb, Wb, out);
    } else {
        hipLaunchKernelGGL(naive_kernel, dim3(NTOK, 4), dim3(256), 0, stream, x, w, out);
    }
}